// Round 1
// baseline (121022.498 us; speedup 1.0000x reference)
//
#include <hip/hip_runtime.h>
#include <hip/hip_cooperative_groups.h>
#include <math.h>

namespace cg = cooperative_groups;

#define S_LEN 4096
#define HID   2048
#define EMBED 4
#define NBLK  256
#define NTHR  512   // 8 waves/block, 1 block/CU

// Decomposition:
//  - block b owns hidden units m in [8b, 8b+8) and the 32 gate columns
//    {gate*2048 + m : gate in 0..3}.  cx for those units never leaves the block.
//  - wave w (0..7) owns local columns cg = 4w..4w+3; cg -> gate = cg>>3, mi = cg&7.
//  - lane l holds W rows k = l + 64*i (i = 0..31) for its 4 columns: 128 VGPRs of W,
//    persistent across all 4096 steps (W never re-read after init).
//  - per step: stage hx (2048 f32) global->LDS, 128 FMAs/lane, 64-lane shuffle
//    reduce, 8 lanes do the LSTM cell math, write 8 hx floats to the global
//    double buffer, grid.sync().

__global__ __launch_bounds__(NTHR, 2)
void qlstm_persistent(const float* __restrict__ inp,     // (S,1,4)
                      const float* __restrict__ conv_w,  // (4)
                      const float* __restrict__ conv_b,  // (1)
                      const float* __restrict__ Wg,      // (2049, 8192) row-major
                      const float* __restrict__ bg,      // (8192)
                      float* __restrict__ out,           // S*H + H + H
                      float* __restrict__ ws)            // scratch
{
    cg::grid_group grid = cg::this_grid();
    const int b   = blockIdx.x;
    const int tid = threadIdx.x;
    const int l   = tid & 63;
    const int wv  = tid >> 6;

    float* conv_s = ws;                  // [S_LEN]
    float* hx0    = ws + S_LEN;          // [HID]  (16 KB offset, 16B aligned)
    float* hx1    = ws + S_LEN + HID;    // [HID]

    __shared__ __align__(16) float hx_lds[HID];
    __shared__ float gates_lds[32];
    __shared__ float colw0[32];
    __shared__ float colb[32];

    // ---------------- init phase ----------------
    {
        const float cw0 = conv_w[0], cw1 = conv_w[1], cw2 = conv_w[2], cw3 = conv_w[3];
        const float cb  = conv_b[0];
        int g = b * NTHR + tid;
        if (g < S_LEN) {
            const float* x = inp + g * EMBED;
            float v = x[0]*cw0 + x[1]*cw1 + x[2]*cw2 + x[3]*cw3 + cb;
            conv_s[g] = 1.0f / (1.0f + expf(-v));   // sigmoid(conv - threshold), thr=0
        }
        if (g < HID) hx0[g] = 0.0f;                 // hx initial state (ws is poisoned)
    }

    // this wave's 4 global column indices
    int jcol[4];
    #pragma unroll
    for (int c = 0; c < 4; ++c) {
        int cgi  = 4*wv + c;
        int gate = cgi >> 3;
        int mi   = cgi & 7;
        jcol[c]  = (gate << 11) + (b * 8 + mi);     // gate*2048 + m
    }
    if (l == 0) {
        #pragma unroll
        for (int c = 0; c < 4; ++c) {
            int cgi = 4*wv + c;
            colw0[cgi] = Wg[jcol[c]];               // row 0 = input (c_t) weight
            colb[cgi]  = bg[jcol[c]];
        }
    }

    // persistent W registers: wreg[c][i] = W[1 + l + 64*i][jcol[c]]
    float wreg[4][32];
    #pragma unroll
    for (int i = 0; i < 32; ++i) {
        const float* rowp = Wg + (size_t)(1 + l + 64*i) * 8192;
        #pragma unroll
        for (int c = 0; c < 4; ++c)
            wreg[c][i] = rowp[jcol[c]];
    }

    float cx = 0.0f;                    // live only in lanes tid<8
    const int m_out = b * 8 + tid;      // hidden index for tid<8

    grid.sync();

    // ---------------- recurrence ----------------
    for (int t = 0; t < S_LEN; ++t) {
        float* hcur = (t & 1) ? hx1 : hx0;
        float* hnxt = (t & 1) ? hx0 : hx1;

        // stage hx into LDS: 512 threads x float4 = 2048 floats, coalesced
        ((float4*)hx_lds)[tid] = ((const float4*)hcur)[tid];
        __syncthreads();

        float acc0 = 0.f, acc1 = 0.f, acc2 = 0.f, acc3 = 0.f;
        #pragma unroll
        for (int i = 0; i < 32; ++i) {
            float h = hx_lds[l + 64*i];   // 2 lanes/bank, different addr: free
            acc0 = fmaf(h, wreg[0][i], acc0);
            acc1 = fmaf(h, wreg[1][i], acc1);
            acc2 = fmaf(h, wreg[2][i], acc2);
            acc3 = fmaf(h, wreg[3][i], acc3);
        }
        // 64-lane reduction
        #pragma unroll
        for (int off = 32; off; off >>= 1) {
            acc0 += __shfl_down(acc0, off, 64);
            acc1 += __shfl_down(acc1, off, 64);
            acc2 += __shfl_down(acc2, off, 64);
            acc3 += __shfl_down(acc3, off, 64);
        }
        if (l == 0) {
            gates_lds[4*wv + 0] = acc0;
            gates_lds[4*wv + 1] = acc1;
            gates_lds[4*wv + 2] = acc2;
            gates_lds[4*wv + 3] = acc3;
        }
        __syncthreads();

        if (tid < 8) {
            float ct = conv_s[t];
            float fg = gates_lds[tid]      + ct*colw0[tid]      + colb[tid];
            float ig = gates_lds[8 + tid]  + ct*colw0[8 + tid]  + colb[8 + tid];
            float gg = gates_lds[16 + tid] + ct*colw0[16 + tid] + colb[16 + tid];
            float og = gates_lds[24 + tid] + ct*colw0[24 + tid] + colb[24 + tid];
            float f  = 1.0f / (1.0f + expf(-fg));
            float ii = 1.0f / (1.0f + expf(-ig));
            float gv = tanhf(gg);
            float o  = 1.0f / (1.0f + expf(-og));
            cx = f * cx + ii * gv;
            float hx = o * tanhf(cx);
            hnxt[m_out] = hx;
            out[(size_t)t * HID + m_out] = hx;
            if (t == S_LEN - 1) {
                out[(size_t)S_LEN * HID + m_out]       = hx;   // final hx
                out[(size_t)S_LEN * HID + HID + m_out] = cx;   // final cx
            }
        }
        grid.sync();   // publishes hnxt device-wide before next step reads it
    }
}

extern "C" void kernel_launch(void* const* d_in, const int* in_sizes, int n_in,
                              void* d_out, int out_size, void* d_ws, size_t ws_size,
                              hipStream_t stream) {
    const float* inp    = (const float*)d_in[0];
    const float* conv_w = (const float*)d_in[1];
    const float* conv_b = (const float*)d_in[2];
    const float* Wg     = (const float*)d_in[3];
    const float* bg     = (const float*)d_in[4];
    float* out = (float*)d_out;
    float* ws  = (float*)d_ws;

    void* args[] = {(void*)&inp, (void*)&conv_w, (void*)&conv_b,
                    (void*)&Wg, (void*)&bg, (void*)&out, (void*)&ws};
    hipLaunchCooperativeKernel((void*)qlstm_persistent,
                               dim3(NBLK), dim3(NTHR), args, 0, stream);
}

// Round 2
// 77139.716 us; speedup vs baseline: 1.5689x; 1.5689x over previous
//
#include <hip/hip_runtime.h>
#include <math.h>

#define S_LEN 4096
#define HID   2048
#define NBLK  256
#define NTHR  512   // 8 waves/block, 1 block/CU

// Decomposition (unchanged from R1):
//  - block b owns hidden units [8b, 8b+8) and their 32 gate columns; cx stays in-block.
//  - lane l of wave w holds W rows k=l+64*i for 4 columns: 128 persistent regs (AGPR-backed).
//  - per step: stage hx global->LDS, 128 FMAs/lane, wave shuffle-reduce, 8 lanes do cell
//    math, publish 8 hx floats, device-wide barrier.
// R2 change: cg::grid.sync() (~28 us/step!) -> hand-rolled monotonic-counter barrier;
//  conv scalars precomputed into per-block LDS; leader arrives without block-wide pre-sync
//  (only wave 0 writes hnxt).

__global__ __launch_bounds__(NTHR, 2)
void qlstm_persistent(const float* __restrict__ inp,     // (S,1,4)
                      const float* __restrict__ conv_w,  // (4)
                      const float* __restrict__ conv_b,  // (1)
                      const float* __restrict__ Wg,      // (2049, 8192) row-major
                      const float* __restrict__ bg,      // (8192)
                      float* __restrict__ out,           // S*H + H + H
                      float* __restrict__ ws)            // scratch (first 1KB zeroed)
{
    const int b   = blockIdx.x;
    const int tid = threadIdx.x;
    const int l   = tid & 63;
    const int wv  = tid >> 6;

    unsigned* bar = (unsigned*)ws;          // [0] monotonic barrier counter
    float* hx0 = ws + 256;                  // [HID] double buffer A
    float* hx1 = ws + 256 + HID + 64;       // [HID] double buffer B (separate lines)

    __shared__ __align__(16) float hx_lds[HID];
    __shared__ __align__(16) float conv_lds[S_LEN];
    __shared__ float gates_lds[32];
    __shared__ float colw0[32];
    __shared__ float colb[32];

    // ---------------- init phase ----------------
    // conv preprocess: every block computes all S steps into its own LDS (one-time).
    {
        const float cw0 = conv_w[0], cw1 = conv_w[1], cw2 = conv_w[2], cw3 = conv_w[3];
        const float cb  = conv_b[0];
        for (int g = tid; g < S_LEN; g += NTHR) {
            float4 x = ((const float4*)inp)[g];
            float v = x.x*cw0 + x.y*cw1 + x.z*cw2 + x.w*cw3 + cb;
            conv_lds[g] = 1.0f / (1.0f + expf(-v));
        }
    }
    // each block zeroes its own 8 hx0 slots (ws is poisoned 0xAA beyond first 1KB)
    if (tid < 8) hx0[b * 8 + tid] = 0.0f;

    // this wave's 4 global column indices
    int jcol[4];
    #pragma unroll
    for (int c = 0; c < 4; ++c) {
        int cgi  = 4*wv + c;
        int gate = cgi >> 3;
        int mi   = cgi & 7;
        jcol[c]  = (gate << 11) + (b * 8 + mi);     // gate*2048 + m
    }
    if (l == 0) {
        #pragma unroll
        for (int c = 0; c < 4; ++c) {
            int cgi = 4*wv + c;
            colw0[cgi] = Wg[jcol[c]];               // row 0 = input (c_t) weight
            colb[cgi]  = bg[jcol[c]];
        }
    }

    // persistent W registers: wreg[c][i] = W[1 + l + 64*i][jcol[c]]
    float wreg[4][32];
    #pragma unroll
    for (int i = 0; i < 32; ++i) {
        const float* rowp = Wg + (size_t)(1 + l + 64*i) * 8192;
        #pragma unroll
        for (int c = 0; c < 4; ++c)
            wreg[c][i] = rowp[jcol[c]];
    }

    float cx = 0.0f;                    // live only in lanes tid<8
    const int m_out = b * 8 + tid;      // hidden index for tid<8

    // ---- fast device-wide barrier (leader arrive + spin, monotonic counter) ----
    unsigned target = NBLK;
    #define GBAR()                                                                 \
        do {                                                                       \
            if (tid == 0) {                                                        \
                __threadfence();  /* release: flush this block's stores */         \
                __hip_atomic_fetch_add(bar, 1u, __ATOMIC_RELAXED,                  \
                                       __HIP_MEMORY_SCOPE_AGENT);                  \
                while (__hip_atomic_load(bar, __ATOMIC_RELAXED,                    \
                                         __HIP_MEMORY_SCOPE_AGENT) < target)       \
                    __builtin_amdgcn_s_sleep(1);                                   \
                __threadfence();  /* acquire: invalidate stale cached lines */     \
            }                                                                      \
            __syncthreads();                                                       \
            target += NBLK;                                                        \
        } while (0)

    GBAR();   // publishes hx0 zeros + waits for all blocks' init

    // ---------------- recurrence ----------------
    for (int t = 0; t < S_LEN; ++t) {
        float* hcur = (t & 1) ? hx1 : hx0;
        float* hnxt = (t & 1) ? hx0 : hx1;

        float ct = conv_lds[t];   // LDS broadcast, off critical path

        // stage hx into LDS: 512 threads x float4 = 2048 floats, coalesced
        ((float4*)hx_lds)[tid] = ((const float4*)hcur)[tid];
        __syncthreads();

        float acc0 = 0.f, acc1 = 0.f, acc2 = 0.f, acc3 = 0.f;
        #pragma unroll
        for (int i = 0; i < 32; ++i) {
            float h = hx_lds[l + 64*i];   // 2 lanes/bank, different addr: free
            acc0 = fmaf(h, wreg[0][i], acc0);
            acc1 = fmaf(h, wreg[1][i], acc1);
            acc2 = fmaf(h, wreg[2][i], acc2);
            acc3 = fmaf(h, wreg[3][i], acc3);
        }
        // 64-lane reduction
        #pragma unroll
        for (int off = 32; off; off >>= 1) {
            acc0 += __shfl_down(acc0, off, 64);
            acc1 += __shfl_down(acc1, off, 64);
            acc2 += __shfl_down(acc2, off, 64);
            acc3 += __shfl_down(acc3, off, 64);
        }
        if (l == 0) {
            gates_lds[4*wv + 0] = acc0;
            gates_lds[4*wv + 1] = acc1;
            gates_lds[4*wv + 2] = acc2;
            gates_lds[4*wv + 3] = acc3;
        }
        __syncthreads();

        // cell math: wave 0 only (lanes 0..7) -> leader can arrive at the barrier
        // without waiting for waves 1..7 (they hold at the barrier's __syncthreads)
        if (tid < 8) {
            float fg = gates_lds[tid]      + ct*colw0[tid]      + colb[tid];
            float ig = gates_lds[8 + tid]  + ct*colw0[8 + tid]  + colb[8 + tid];
            float gg = gates_lds[16 + tid] + ct*colw0[16 + tid] + colb[16 + tid];
            float og = gates_lds[24 + tid] + ct*colw0[24 + tid] + colb[24 + tid];
            float f  = 1.0f / (1.0f + expf(-fg));
            float ii = 1.0f / (1.0f + expf(-ig));
            float gv = tanhf(gg);
            float o  = 1.0f / (1.0f + expf(-og));
            cx = f * cx + ii * gv;
            float hx = o * tanhf(cx);
            hnxt[m_out] = hx;
            out[(size_t)t * HID + m_out] = hx;
            if (t == S_LEN - 1) {
                out[(size_t)S_LEN * HID + m_out]       = hx;   // final hx
                out[(size_t)S_LEN * HID + HID + m_out] = cx;   // final cx
            }
        }
        GBAR();   // publishes hnxt device-wide before next step reads it
    }
    #undef GBAR
}

extern "C" void kernel_launch(void* const* d_in, const int* in_sizes, int n_in,
                              void* d_out, int out_size, void* d_ws, size_t ws_size,
                              hipStream_t stream) {
    const float* inp    = (const float*)d_in[0];
    const float* conv_w = (const float*)d_in[1];
    const float* conv_b = (const float*)d_in[2];
    const float* Wg     = (const float*)d_in[3];
    const float* bg     = (const float*)d_in[4];
    float* out = (float*)d_out;
    float* ws  = (float*)d_ws;

    // zero the barrier counter region (ws is re-poisoned 0xAA before every launch)
    hipMemsetAsync(ws, 0, 1024, stream);

    void* args[] = {(void*)&inp, (void*)&conv_w, (void*)&conv_b,
                    (void*)&Wg, (void*)&bg, (void*)&out, (void*)&ws};
    hipLaunchCooperativeKernel((void*)qlstm_persistent,
                               dim3(NBLK), dim3(NTHR), args, 0, stream);
}